// Round 1
// baseline (988.374 us; speedup 1.0000x reference)
//
#include <hip/hip_runtime.h>
#include <math.h>

#define GXD 128
#define GYD 128
#define GZD 32
#define DD  64
#define GCELLS (GXD * GYD * GZD)   // 524288

#define MINX (-20.0f)
#define MINY (-20.0f)
#define MINZ (-2.0f)
#define VOXX (0.3125f)
#define VOXY (0.3125f)
#define VOXZ (0.25f)
#define ELL  (0.5f)
#define EPSV (1e-6f)
#define PIF  (3.14159265358979323846f)

// ---------------------------------------------------------------------------
// Accumulation: one 64-lane wave per point; lane d owns feature d.
// Scatters three moments with f32 global atomics:
//   y_sum[g][d]  += kval * f[d]     (stored in out_mean region)
//   sq_sum[g][d] += kval * f[d]^2   (stored in out_var region)
//   k_bar[g]     += kval            (stored in out_conf region)
// ---------------------------------------------------------------------------
__global__ void lbki_accum(const float* __restrict__ pc,
                           float* __restrict__ y_sum,
                           float* __restrict__ sq_sum,
                           float* __restrict__ k_bar,
                           int npts) {
    __shared__ float kval_s[27];
    int tid = threadIdx.x;
    if (tid < 27) {
        int ox = tid / 9 - 1;
        int oy = (tid / 3) % 3 - 1;
        int oz = tid % 3 - 1;
        float dx = ox * VOXX, dy = oy * VOXY, dz = oz * VOXZ;
        float d = sqrtf(dx * dx + dy * dy + dz * dz);
        float ang = 2.0f * PIF * d / ELL;
        float v = (1.0f / 3.0f) * (2.0f + cosf(ang)) * (1.0f - d / ELL)
                + (1.0f / (2.0f * PIF)) * sinf(ang);
        v = (d >= ELL) ? 0.0f : v;
        v = fminf(fmaxf(v, 0.0f), 1.0f);
        kval_s[tid] = v;
    }
    __syncthreads();

    int lane = tid & 63;
    int wave = tid >> 6;
    int waves_per_block = blockDim.x >> 6;
    int p = blockIdx.x * waves_per_block + wave;
    if (p >= npts) return;

    const float* row = pc + (size_t)p * 67;
    // xyz: wave-uniform broadcast loads
    float x = row[0], y = row[1], z = row[2];
    float f = row[3 + lane];
    float kf2 = f * f;

    // match reference arithmetic exactly: floor((xyz - MIN_B) / VOX)
    int gx = (int)floorf((x - MINX) / VOXX);
    int gy = (int)floorf((y - MINY) / VOXY);
    int gz = (int)floorf((z - MINZ) / VOXZ);

    #pragma unroll
    for (int o = 0; o < 27; ++o) {
        float kv = kval_s[o];
        if (kv <= 0.0f) continue;                       // 8 corners: kval == 0
        int nx = gx + (o / 9) - 1;
        int ny = gy + ((o / 3) % 3) - 1;
        int nz = gz + (o % 3) - 1;
        if ((unsigned)nx >= (unsigned)GXD) continue;    // wave-uniform branches
        if ((unsigned)ny >= (unsigned)GYD) continue;
        if ((unsigned)nz >= (unsigned)GZD) continue;
        size_t g = ((size_t)nx * GYD + ny) * GZD + nz;
        atomicAdd(&y_sum[g * DD + lane], kv * f);
        atomicAdd(&sq_sum[g * DD + lane], kv * kf2);
        if (lane == 0) atomicAdd(&k_bar[g], kv);
    }
}

// ---------------------------------------------------------------------------
// Finalize: one 64-lane wave per cell; lane d owns feature d.
// Reads the three accumulated moments (in the output regions) + the input
// maps and writes the fused outputs in place.
//   y_bar = y_sum / (k_bar + EPS)
//   S_bar = sq_sum - 2*y_bar*y_sum + y_bar^2*k_bar      (exact expansion)
// ---------------------------------------------------------------------------
__global__ void lbki_finalize(const float* __restrict__ mean_map,
                              const float* __restrict__ var_map,
                              const float* __restrict__ conf_map,
                              float* __restrict__ out_mean,   // holds y_sum
                              float* __restrict__ out_var,    // holds sq_sum
                              float* __restrict__ out_conf) { // holds k_bar
    int lane = threadIdx.x & 63;
    int wave = threadIdx.x >> 6;
    int g = blockIdx.x * (blockDim.x >> 6) + wave;
    if (g >= GCELLS) return;

    float kb   = out_conf[g];      // broadcast read before lane-0 write below
    float conf = conf_map[g];

    size_t idx = (size_t)g * DD + lane;
    float ys   = out_mean[idx];
    float sq   = out_var[idx];
    float mean = mean_map[idx];
    float var  = var_map[idx];

    float ybar  = ys / (kb + EPSV);
    float Sbar  = sq - 2.0f * ybar * ys + ybar * ybar * kb;
    float denom = conf + kb + EPSV;
    float dm    = ybar - mean;
    float scal  = conf * kb / denom;

    out_mean[idx] = (conf * mean + kb * ybar) / denom;
    out_var[idx]  = var + Sbar + scal * dm * dm;
    if (lane == 0) out_conf[g] = conf + kb;
}

extern "C" void kernel_launch(void* const* d_in, const int* in_sizes, int n_in,
                              void* d_out, int out_size, void* d_ws, size_t ws_size,
                              hipStream_t stream) {
    const float* mean_map = (const float*)d_in[0];
    const float* var_map  = (const float*)d_in[1];
    const float* conf_map = (const float*)d_in[2];
    const float* pc       = (const float*)d_in[3];
    int npts = in_sizes[3] / 67;

    float* out      = (float*)d_out;
    float* out_mean = out;                          // G*D  (y_sum during accum)
    float* out_var  = out + (size_t)GCELLS * DD;    // G*D  (sq_sum during accum)
    float* out_conf = out + (size_t)2 * GCELLS * DD;// G    (k_bar during accum)

    // zero the accumulators (the whole output buffer)
    hipMemsetAsync(d_out, 0, (size_t)out_size * sizeof(float), stream);

    // accumulation: 4 waves (points) per 256-thread block
    int waves_per_block = 4;
    int blocks = (npts + waves_per_block - 1) / waves_per_block;
    lbki_accum<<<blocks, 256, 0, stream>>>(pc, out_mean, out_var, out_conf, npts);

    // finalize: 4 cells per 256-thread block
    int fblocks = GCELLS / 4;
    lbki_finalize<<<fblocks, 256, 0, stream>>>(mean_map, var_map, conf_map,
                                               out_mean, out_var, out_conf);
}

// Round 2
// 735.821 us; speedup vs baseline: 1.3432x; 1.3432x over previous
//
#include <hip/hip_runtime.h>
#include <math.h>

#define GXD 128
#define GYD 128
#define GZD 32
#define DD  64
#define GCELLS (GXD * GYD * GZD)   // 524288

#define MINX (-20.0f)
#define MINY (-20.0f)
#define MINZ (-2.0f)
#define VOXX (0.3125f)
#define VOXY (0.3125f)
#define VOXZ (0.25f)
#define ELL  (0.5f)
#define EPSV (1e-6f)
#define PIF  (3.14159265358979323846f)

// kval for offset index o in [0,27): (ox,oy,oz) = (o/9-1, (o/3)%3-1, o%3-1)
__device__ __forceinline__ float kval_of(int o) {
    int ox = o / 9 - 1;
    int oy = (o / 3) % 3 - 1;
    int oz = o % 3 - 1;
    float dx = ox * VOXX, dy = oy * VOXY, dz = oz * VOXZ;
    float d = sqrtf(dx * dx + dy * dy + dz * dz);
    float ang = 2.0f * PIF * d / ELL;
    float v = (1.0f / 3.0f) * (2.0f + cosf(ang)) * (1.0f - d / ELL)
            + (1.0f / (2.0f * PIF)) * sinf(ang);
    v = (d >= ELL) ? 0.0f : v;
    return fminf(fmaxf(v, 0.0f), 1.0f);
}

__device__ __forceinline__ int base_cell(const float* __restrict__ row,
                                         int* cx, int* cy, int* cz) {
    float x = row[0], y = row[1], z = row[2];
    int gx = (int)floorf((x - MINX) / VOXX);
    int gy = (int)floorf((y - MINY) / VOXY);
    int gz = (int)floorf((z - MINZ) / VOXZ);
    // defensive clamp (inputs are strictly in-bounds)
    gx = min(max(gx, 0), GXD - 1);
    gy = min(max(gy, 0), GYD - 1);
    gz = min(max(gz, 0), GZD - 1);
    *cx = gx; *cy = gy; *cz = gz;
    return (gx * GYD + gy) * GZD + gz;
}

// ===========================================================================
// FAST PATH (needs ~271 MB workspace)
// ===========================================================================

// Pass 1: zero only the M1/M2 rows of touched base cells (races benign: all 0)
__global__ void lbki_zero_rows(const float* __restrict__ pc,
                               float* __restrict__ M1,
                               float* __restrict__ M2,
                               int npts) {
    int lane = threadIdx.x & 63;
    int wave = threadIdx.x >> 6;
    int p = blockIdx.x * (blockDim.x >> 6) + wave;
    if (p >= npts) return;
    int cx, cy, cz;
    int g = base_cell(pc + (size_t)p * 67, &cx, &cy, &cz);
    size_t idx = (size_t)g * DD + lane;
    M1[idx] = 0.0f;
    M2[idx] = 0.0f;
}

// Pass 2: scatter per-point raw moments into the BASE cell only.
__global__ void lbki_build(const float* __restrict__ pc,
                           float* __restrict__ M0,
                           float* __restrict__ M1,
                           float* __restrict__ M2,
                           int npts) {
    int lane = threadIdx.x & 63;
    int wave = threadIdx.x >> 6;
    int p = blockIdx.x * (blockDim.x >> 6) + wave;
    if (p >= npts) return;
    const float* row = pc + (size_t)p * 67;
    int cx, cy, cz;
    int g = base_cell(row, &cx, &cy, &cz);
    float f = row[3 + lane];
    size_t idx = (size_t)g * DD + lane;
    atomicAdd(&M1[idx], f);
    atomicAdd(&M2[idx], f * f);
    if (lane == 0) atomicAdd(&M0[g], 1.0f);
}

// Pass 3: 19-tap stencil over base-cell moments, fused with finalize math.
// One wave per cell; lane d owns feature d. Taps guarded by M0==0.
__global__ void lbki_stencil(const float* __restrict__ M0,
                             const float* __restrict__ M1,
                             const float* __restrict__ M2,
                             const float* __restrict__ mean_map,
                             const float* __restrict__ var_map,
                             const float* __restrict__ conf_map,
                             float* __restrict__ out_mean,
                             float* __restrict__ out_var,
                             float* __restrict__ out_conf) {
    __shared__ float kval_s[27];
    if (threadIdx.x < 27) kval_s[threadIdx.x] = kval_of(threadIdx.x);
    __syncthreads();

    int lane = threadIdx.x & 63;
    int wave = threadIdx.x >> 6;

    // bijective XCD swizzle: gridDim.x % 8 == 0; each XCD gets a contiguous
    // x-slab so its 3-plane stencil front (~2.4 MB) fits its private L2.
    unsigned b = blockIdx.x;
    unsigned chunk = gridDim.x >> 3;
    unsigned swz = (b & 7) * chunk + (b >> 3);

    int g = (int)(swz * (blockDim.x >> 6) + wave);
    int cz = g & (GZD - 1);
    int cy = (g >> 5) & (GYD - 1);
    int cx = g >> 12;

    float acc_y = 0.0f, acc_s = 0.0f, acc_k = 0.0f;

    #pragma unroll
    for (int o = 0; o < 27; ++o) {
        float kv = kval_s[o];
        if (kv <= 0.0f) continue;               // 8 corners (wave-uniform)
        int nx = cx + (o / 9) - 1;
        int ny = cy + ((o / 3) % 3) - 1;
        int nz = cz + (o % 3) - 1;
        if ((unsigned)nx >= (unsigned)GXD) continue;
        if ((unsigned)ny >= (unsigned)GYD) continue;
        if ((unsigned)nz >= (unsigned)GZD) continue;
        int gn = (nx * GYD + ny) * GZD + nz;
        float cnt = M0[gn];                      // uniform broadcast load
        if (cnt == 0.0f) continue;               // unpopulated: skip 512B
        acc_k += kv * cnt;
        size_t nidx = (size_t)gn * DD + lane;
        acc_y += kv * M1[nidx];
        acc_s += kv * M2[nidx];
    }

    size_t idx = (size_t)g * DD + lane;
    float conf = conf_map[g];
    float mean = mean_map[idx];
    float var  = var_map[idx];

    float kb    = acc_k;
    float ybar  = acc_y / (kb + EPSV);
    float Sbar  = acc_s - 2.0f * ybar * acc_y + ybar * ybar * kb;
    float denom = conf + kb + EPSV;
    float dm    = ybar - mean;
    float scal  = conf * kb / denom;

    out_mean[idx] = (conf * mean + kb * ybar) / denom;
    out_var[idx]  = var + Sbar + scal * dm * dm;
    if (lane == 0) out_conf[g] = conf + kb;
}

// ===========================================================================
// FALLBACK PATH (round-1 kernels, used only if workspace is too small)
// ===========================================================================
__global__ void lbki_accum(const float* __restrict__ pc,
                           float* __restrict__ y_sum,
                           float* __restrict__ sq_sum,
                           float* __restrict__ k_bar,
                           int npts) {
    __shared__ float kval_s[27];
    if (threadIdx.x < 27) kval_s[threadIdx.x] = kval_of(threadIdx.x);
    __syncthreads();

    int lane = threadIdx.x & 63;
    int wave = threadIdx.x >> 6;
    int p = blockIdx.x * (blockDim.x >> 6) + wave;
    if (p >= npts) return;

    const float* row = pc + (size_t)p * 67;
    int gx, gy, gz;
    base_cell(row, &gx, &gy, &gz);
    float f = row[3 + lane];
    float ff = f * f;

    #pragma unroll
    for (int o = 0; o < 27; ++o) {
        float kv = kval_s[o];
        if (kv <= 0.0f) continue;
        int nx = gx + (o / 9) - 1;
        int ny = gy + ((o / 3) % 3) - 1;
        int nz = gz + (o % 3) - 1;
        if ((unsigned)nx >= (unsigned)GXD) continue;
        if ((unsigned)ny >= (unsigned)GYD) continue;
        if ((unsigned)nz >= (unsigned)GZD) continue;
        size_t g = ((size_t)nx * GYD + ny) * GZD + nz;
        atomicAdd(&y_sum[g * DD + lane], kv * f);
        atomicAdd(&sq_sum[g * DD + lane], kv * ff);
        if (lane == 0) atomicAdd(&k_bar[g], kv);
    }
}

__global__ void lbki_finalize(const float* __restrict__ mean_map,
                              const float* __restrict__ var_map,
                              const float* __restrict__ conf_map,
                              float* __restrict__ out_mean,
                              float* __restrict__ out_var,
                              float* __restrict__ out_conf) {
    int lane = threadIdx.x & 63;
    int wave = threadIdx.x >> 6;
    int g = blockIdx.x * (blockDim.x >> 6) + wave;
    if (g >= GCELLS) return;

    float kb   = out_conf[g];
    float conf = conf_map[g];

    size_t idx = (size_t)g * DD + lane;
    float ys   = out_mean[idx];
    float sq   = out_var[idx];
    float mean = mean_map[idx];
    float var  = var_map[idx];

    float ybar  = ys / (kb + EPSV);
    float Sbar  = sq - 2.0f * ybar * ys + ybar * ybar * kb;
    float denom = conf + kb + EPSV;
    float dm    = ybar - mean;
    float scal  = conf * kb / denom;

    out_mean[idx] = (conf * mean + kb * ybar) / denom;
    out_var[idx]  = var + Sbar + scal * dm * dm;
    if (lane == 0) out_conf[g] = conf + kb;
}

// ===========================================================================
extern "C" void kernel_launch(void* const* d_in, const int* in_sizes, int n_in,
                              void* d_out, int out_size, void* d_ws, size_t ws_size,
                              hipStream_t stream) {
    const float* mean_map = (const float*)d_in[0];
    const float* var_map  = (const float*)d_in[1];
    const float* conf_map = (const float*)d_in[2];
    const float* pc       = (const float*)d_in[3];
    int npts = in_sizes[3] / 67;

    float* out      = (float*)d_out;
    float* out_mean = out;
    float* out_var  = out + (size_t)GCELLS * DD;
    float* out_conf = out + (size_t)2 * GCELLS * DD;

    const size_t WS_NEEDED = ((size_t)GCELLS + 2 * (size_t)GCELLS * DD) * sizeof(float);

    if (ws_size >= WS_NEEDED) {
        // ---- fast path: base-cell moments + stencil ----
        float* M0 = (float*)d_ws;                         // G        (counts)
        float* M1 = M0 + GCELLS;                          // G*D      (sum f)
        float* M2 = M1 + (size_t)GCELLS * DD;             // G*D      (sum f^2)

        hipMemsetAsync(M0, 0, (size_t)GCELLS * sizeof(float), stream);

        int wpb = 4;  // waves (points) per 256-thread block
        int pblocks = (npts + wpb - 1) / wpb;
        lbki_zero_rows<<<pblocks, 256, 0, stream>>>(pc, M1, M2, npts);
        lbki_build<<<pblocks, 256, 0, stream>>>(pc, M0, M1, M2, npts);

        int sblocks = GCELLS / 4;   // 131072, divisible by 8 for the swizzle
        lbki_stencil<<<sblocks, 256, 0, stream>>>(M0, M1, M2,
                                                  mean_map, var_map, conf_map,
                                                  out_mean, out_var, out_conf);
    } else {
        // ---- fallback: round-1 atomic scatter ----
        hipMemsetAsync(d_out, 0, (size_t)out_size * sizeof(float), stream);
        int wpb = 4;
        int blocks = (npts + wpb - 1) / wpb;
        lbki_accum<<<blocks, 256, 0, stream>>>(pc, out_mean, out_var, out_conf, npts);
        int fblocks = GCELLS / 4;
        lbki_finalize<<<fblocks, 256, 0, stream>>>(mean_map, var_map, conf_map,
                                                   out_mean, out_var, out_conf);
    }
}